// Round 17
// baseline (70.329 us; speedup 1.0000x reference)
//
#include <hip/hip_runtime.h>

#define IMG   384
#define IMG4  96
#define IMG2  (IMG*IMG)
#define CROP  378
#define NB    64
#define NGRP  16
#define NROWS 24
#define TILES 3           // 3 tiles x 8 rows = 24 rows per block
#define TROWS 8
#define NTH   512         // 8 waves, wave = row within tile
#define PSTR  520         // 256 D + 8 Tq2 + 252 edges + pad

typedef __fp16 half8  __attribute__((ext_vector_type(8)));
typedef __fp16 f16x2  __attribute__((ext_vector_type(2)));
typedef float  floatx4 __attribute__((ext_vector_type(4)));

__device__ __forceinline__ unsigned pkh(float a, float b) {
    f16x2 h = __builtin_amdgcn_cvt_pkrtz(a, b);
    return __builtin_bit_cast(unsigned, h);
}

// R17: occupancy + burst-staging restructure of the verified MFMA scheme.
//   A rows 0..6 = q[r+i][u], 7..13 = mask[r+i][u], 14 = ones, 15 = zero
//   B cols 0..6 = p[r][u-j], 7..13 = p^2[r][u-j], 14 = ones, 15 = zero
//   D[i][j]=A, D[7+i][j]=C, D[7+i][7+j]=B, D[i][14]=Tq(i), D[7+i][14]=Tm(i),
//   D[14][0]=Sp.  Tq2(i) from f32 per-row q^2 sums (rowQ2, per tile).
// Block = 3 sequential 8-row tiles; every record quantity is additive over
// rows, so D / edges / Tq2 accumulate across tiles into one record.
// Per tile: stage q/m rels 0..14 (direct slots, no circular indexing) and
// p rels 0..7 in one big-MLP burst -> barrier -> 8 waves x 12 MFMA slices +
// edge reads -> barrier. LDS 36.5 KB -> 4 blocks/CU x 8 waves = 32 slots/CU.
__global__ __launch_bounds__(NTH)
void corr_kernel(const float* __restrict__ sr, const float* __restrict__ hr,
                 const float* __restrict__ mk, float* __restrict__ part)
{
    __shared__ __align__(16) char qpl [15*784];
    __shared__ __align__(16) char mpl [15*784];
    __shared__ __align__(16) char ppool[2*8*800 + 16];  // p2 staggered +16B
    __shared__ float rowQ2[TILES][16];
    char* const ppl  = ppool;
    char* const p2pl = ppool + 8*800 + 16;

    const int tid = threadIdx.x;
    // XCD-clustered: all 16 blocks of a batch on one XCD class
    const int id  = blockIdx.x;
    const int c8  = id & 7;
    const int k0  = id >> 3;              // 0..127
    const int b   = c8 + 8 * (k0 >> 4);
    const int grp = k0 & 15;
    const int c0  = grp * NROWS;
    const int nvalid = (CROP - c0 < NROWS) ? (CROP - c0) : NROWS;

    const float*  sb   = sr + (size_t)b * IMG2;
    const float*  mown = mk + (size_t)b * IMG2;
    const float4* hb4  = (const float4*)(hr + (size_t)b * IMG2);
    const float4* mb4  = (const float4*)(mk + (size_t)b * IMG2);

    const int wid  = tid >> 6;            // 0..7 = row within tile
    const int lane = tid & 63;
    const int m16  = lane & 15;
    const int g    = lane >> 4;

    floatx4 D0 = {0.f, 0.f, 0.f, 0.f};
    floatx4 D1 = {0.f, 0.f, 0.f, 0.f};

    const uint4 onesbits = {0x3C003C00u, 0x3C003C00u, 0x3C003C00u, 0x3C003C00u};
    const uint4 zerobits = {0u, 0u, 0u, 0u};
    const half8 ones8 = __builtin_bit_cast(half8, onesbits);
    const half8 zero8 = __builtin_bit_cast(half8, zerobits);

    // edge slot: thread (i, t, kind) accumulates plane value at edge col
    float eacc = 0.f;
    int ei = 0, et = 0, ek = 0, ecolByte = 0;
    if (tid < 252) {
        ei = tid / 36; const int rem = tid % 36; et = rem % 12; ek = rem / 12;
        const int ec = (et < 6) ? et : (372 + et);
        ecolByte = 2 * ec;
    }

    // ---- prologue: zero rowQ2 + p-plane pads ----
    if (tid < TILES*16) ((float*)rowQ2)[tid] = 0.f;
    if (tid < 8*2*11) {                                   // p-plane pad dwords
        const int slot = tid / 22, rem = tid % 22;
        const int pl = rem / 11, kk = rem % 11;
        const int dd = (kk < 4) ? kk : (189 + kk);        // 0..3, 193..199
        *(unsigned*)((pl ? p2pl : ppl) + slot*800 + 4*dd) = 0u;
    }
    __syncthreads();

    // ---- 3 tiles, each: burst-stage -> barrier -> MFMA+edges -> barrier ----
    for (int t = 0; t < TILES; ++t) {
        const int r0 = TROWS * t;                         // crop-row base in block

        // stage q/m rels 0..14 (15 rows) — direct slots
        for (int idx = tid; idx < 15*96; idx += NTH) {
            const int rw = idx / 96, c = idx % 96;
            int w = c0 + r0 + rw; if (w > 383) w = 383;   // clamp load only
            const float4 hv = hb4[(size_t)w * IMG4 + c];
            const float4 mv = mb4[(size_t)w * IMG4 + c];
            const float qx = hv.x*mv.x, qy = hv.y*mv.y;
            const float qz = hv.z*mv.z, qw = hv.w*mv.w;
            *(uint2*)(qpl + rw*784 + c*8) = make_uint2(pkh(qx, qy), pkh(qz, qw));
            *(uint2*)(mpl + rw*784 + c*8) = make_uint2(pkh(mv.x, mv.y), pkh(mv.z, mv.w));
            atomicAdd(&rowQ2[t][rw], qx*qx + qy*qy + qz*qz + qw*qw);
        }
        // stage p rels 0..7 (crop rows c0+r0 .. +7, clamped)
        for (int idx = tid; idx < 8*189; idx += NTH) {
            const int rw = idx / 189, d = 4 + idx % 189;  // x-dwords 4..192
            int rc = r0 + rw; if (c0 + rc > 377) rc = 377 - c0;
            const int v0 = 2*d - 8;
            const float* srow = sb   + (size_t)(c0 + rc + 3) * IMG + (v0 + 3);
            const float* mrow = mown + (size_t)(c0 + rc + 3) * IMG + (v0 + 3);
            const float p0 = srow[0] * mrow[0], p1 = srow[1] * mrow[1];
            *(unsigned*)(ppl  + rw*800 + 4*d) = pkh(p0, p1);
            *(unsigned*)(p2pl + rw*800 + 4*d) = pkh(p0*p0, p1*p1);
        }
        __syncthreads();

        // compute: wave wid = crop row r0+wid
        if (r0 + wid < nvalid) {
            const int mm = (m16 < 7) ? m16 : (m16 - 7);
            const char* aB = ((m16 < 7) ? qpl : mpl) + (wid + mm)*784;
            const char* bB = ((m16 < 7) ? ppl : p2pl) + wid*800;
            const int Sb = 16 - 2*mm + g*16;
            #pragma unroll
            for (int sl = 0; sl < 12; ++sl) {
                half8 av, bv;
                if (m16 < 14) {
                    av = *(const half8*)(aB + sl*64 + g*16);
                    const int S  = Sb + sl*64;
                    const int S0 = S & ~3;
                    const unsigned sh = (unsigned)((S & 2) << 3);
                    const unsigned* bw = (const unsigned*)(bB + S0);
                    const unsigned d0 = bw[0], d1 = bw[1], d2 = bw[2], d3 = bw[3], d4 = bw[4];
                    uint4 bi;
                    bi.x = __builtin_amdgcn_alignbit(d1, d0, sh);
                    bi.y = __builtin_amdgcn_alignbit(d2, d1, sh);
                    bi.z = __builtin_amdgcn_alignbit(d3, d2, sh);
                    bi.w = __builtin_amdgcn_alignbit(d4, d3, sh);
                    bv = __builtin_bit_cast(half8, bi);
                } else if (m16 == 14) {
                    av = ones8; bv = ones8;
                } else {
                    av = zero8; bv = zero8;
                }
                if (sl & 1) D1 = __builtin_amdgcn_mfma_f32_16x16x32_f16(av, bv, D1, 0, 0, 0);
                else        D0 = __builtin_amdgcn_mfma_f32_16x16x32_f16(av, bv, D0, 0, 0, 0);
            }
        }

        // edges: window rows rel rr+ei for valid crop rows of this tile
        if (tid < 252) {
            #pragma unroll
            for (int rr = 0; rr < TROWS; ++rr) {
                if (r0 + rr < nvalid) {
                    const int slot = rr + ei;             // <= 13 < 15
                    const char* pl = (ek == 0) ? mpl : qpl;
                    const float v = (float)*(const __fp16*)(pl + slot*784 + ecolByte);
                    eacc += (ek == 2) ? v*v : v;
                }
            }
        }
        __syncthreads();      // protect planes from next tile's staging
    }

    // ---- epilogue: reduce 8 waves' D (wred overlaid on dead p-planes) ----
    float* wred = (float*)ppool;              // 8*256 floats = 8 KB
    {
        const floatx4 D = D0 + D1;
        const int rb = (lane >> 4) * 4, col = lane & 15;
        #pragma unroll
        for (int k = 0; k < 4; ++k)
            wred[wid*256 + (rb + k)*16 + col] = D[k];
    }
    __syncthreads();
    float* po = part + (size_t)(b * NGRP + grp) * PSTR;
    if (tid < 256) {
        float v = 0.f;
        #pragma unroll
        for (int w = 0; w < 8; ++w) v += wred[w*256 + tid];
        po[tid] = v;
    }
    if (tid < 7) {
        float acc = 0.f;
        for (int t = 0; t < TILES; ++t) {
            int vt = nvalid - TROWS*t;
            vt = (vt < 0) ? 0 : (vt > TROWS ? TROWS : vt);
            for (int k = 0; k < vt; ++k) acc += rowQ2[t][tid + k];
        }
        po[256 + tid] = acc;
    }
    if (tid < 252)
        po[264 + ek*84 + ei*12 + et] = eacc;
}

__global__ __launch_bounds__(256)
void mse_kernel(const float* __restrict__ part, double* __restrict__ bmin)
{
    __shared__ double chunk[4][49][7];
    const int b   = blockIdx.x;
    const int tid = threadIdx.x;
    const int s   = tid & 63;            // shift 0..48 active
    const int cc  = tid >> 6;            // group chunk 0..3

    if (s < 49) {
        const int i = s / 7, j = s % 7;
        double A=0, Bc=0, Cc=0, Tm=0, Tq=0, Tq2=0, Sp=0;
        for (int gg = cc*4; gg < cc*4 + 4; ++gg) {
            const float* p = part + (size_t)(b * NGRP + gg) * PSTR;
            A   += p[i*16 + j];
            Cc  += p[(7+i)*16 + j];
            Bc  += p[(7+i)*16 + 7 + j];
            Tq  += p[i*16 + 14];
            Tm  += p[(7+i)*16 + 14];
            Sp  += p[14*16 + 0];
            Tq2 += p[256 + i];
            #pragma unroll
            for (int t = 0; t < 12; ++t) {
                if (t < j || t >= j + 6) {   // col outside x-window [j, j+377]
                    Tm  -= p[264 +      i*12 + t];
                    Tq  -= p[264 + 84 + i*12 + t];
                    Tq2 -= p[264 +168 + i*12 + t];
                }
            }
        }
        chunk[cc][s][0] = A;  chunk[cc][s][1] = Bc; chunk[cc][s][2] = Cc;
        chunk[cc][s][3] = Tm; chunk[cc][s][4] = Tq; chunk[cc][s][5] = Tq2;
        chunk[cc][s][6] = Sp;
    }
    __syncthreads();

    if (tid < 64) {
        double mse = 1e300;
        if (tid < 49) {
            double v[7];
            #pragma unroll
            for (int q = 0; q < 7; ++q)
                v[q] = chunk[0][tid][q] + chunk[1][tid][q] + chunk[2][tid][q] + chunk[3][tid][q];
            const double A = v[0], Bc = v[1], Cc = v[2], Tm = v[3];
            const double Tq = v[4], Tq2 = v[5], Sp = v[6];
            const double bb = (Tq - Sp) / Tm;
            mse = (Tq2 - 2.0*A - 2.0*bb*Tq + Bc + 2.0*bb*Cc + bb*bb*Tm) / Tm;
        }
        for (int off = 32; off; off >>= 1) {
            const double o = __shfl_down(mse, off);
            mse = fmin(mse, o);
        }
        if (tid == 0) bmin[b] = mse;
    }
}

__global__ __launch_bounds__(64)
void mean_kernel(const double* __restrict__ bmin, float* __restrict__ out)
{
    double v = bmin[threadIdx.x];
    for (int off = 32; off; off >>= 1) v += __shfl_down(v, off);
    if (threadIdx.x == 0) out[0] = (float)(v / 64.0);
}

extern "C" void kernel_launch(void* const* d_in, const int* in_sizes, int n_in,
                              void* d_out, int out_size, void* d_ws, size_t ws_size,
                              hipStream_t stream) {
    const float* sr = (const float*)d_in[0];
    const float* hr = (const float*)d_in[1];
    const float* mk = (const float*)d_in[2];

    float* part = (float*)d_ws;
    const size_t part_bytes = (size_t)NB * NGRP * PSTR * sizeof(float); // 2129920
    double* bmin = (double*)((char*)d_ws + part_bytes);

    corr_kernel<<<dim3(NB * NGRP), NTH, 0, stream>>>(sr, hr, mk, part);
    mse_kernel<<<dim3(NB), 256, 0, stream>>>(part, bmin);
    mean_kernel<<<dim3(1), 64, 0, stream>>>(bmin, (float*)d_out);
}

// Round 18
// 69.086 us; speedup vs baseline: 1.0180x; 1.0180x over previous
//
#include <hip/hip_runtime.h>

#define IMG   384
#define IMG4  96
#define IMG2  (IMG*IMG)
#define CROP  378
#define NB    64
#define NGRP  16
#define NROWS 24
#define TILES 3           // 3 tiles x 8 rows = 24 rows per block
#define TROWS 8
#define NTH   512         // 8 waves, wave = row within tile
#define PSTR  520         // 256 D + 8 Tq2 + 252 edges + pad
#define NQM   (14*96)     // q/m f4-cols staged per tile (rows 0..13)
#define NP    (8*189)     // p dword items per tile

typedef __fp16 half8  __attribute__((ext_vector_type(8)));
typedef __fp16 f16x2  __attribute__((ext_vector_type(2)));
typedef float  floatx4 __attribute__((ext_vector_type(4)));

__device__ __forceinline__ unsigned pkh(float a, float b) {
    f16x2 h = __builtin_amdgcn_cvt_pkrtz(a, b);
    return __builtin_bit_cast(unsigned, h);
}

// R18 = R17 tile structure (high occupancy, tiny base VGPR) + R15's proven
// cross-barrier 2-deep prefetch (loads for tile t+1 issued while tile t
// computes; consumed at next iteration's write, behind a __syncthreads the
// compiler cannot hoist loads across — R15 evidence: VGPR 60->80 pin).
// MFMA formulation (verified R10+):
//   A rows 0..6 = q[r+i][u], 7..13 = mask[r+i][u], 14 = ones, 15 = zero
//   B cols 0..6 = p[r][u-j], 7..13 = p^2[r][u-j], 14 = ones, 15 = zero
//   D[i][j]=A, D[7+i][j]=C, D[7+i][7+j]=B, D[i][14]=Tq(i), D[7+i][14]=Tm(i),
//   D[14][0]=Sp.  Tq2(i) from f32 per-row q^2 sums (rowQ2, per tile).
// Per tile: write(regs->LDS, 14 q/m rows + 8 p rows) -> barrier ->
// {issue next tile's loads; 8 waves x 12 MFMA slices; edge reads} -> barrier.
__global__ __launch_bounds__(NTH, 4)
void corr_kernel(const float* __restrict__ sr, const float* __restrict__ hr,
                 const float* __restrict__ mk, float* __restrict__ part)
{
    __shared__ __align__(16) char qpl [14*784];
    __shared__ __align__(16) char mpl [14*784];
    __shared__ __align__(16) char ppool[2*8*800 + 16];  // p2 staggered +16B
    __shared__ float rowQ2[TILES][16];
    char* const ppl  = ppool;
    char* const p2pl = ppool + 8*800 + 16;

    const int tid = threadIdx.x;
    // XCD-clustered: all 16 blocks of a batch on one XCD class
    const int id  = blockIdx.x;
    const int c8  = id & 7;
    const int k0  = id >> 3;              // 0..127
    const int b   = c8 + 8 * (k0 >> 4);
    const int grp = k0 & 15;
    const int c0  = grp * NROWS;
    const int nvalid = (CROP - c0 < NROWS) ? (CROP - c0) : NROWS;

    const float*  sb   = sr + (size_t)b * IMG2;
    const float*  mown = mk + (size_t)b * IMG2;
    const float4* hb4  = (const float4*)(hr + (size_t)b * IMG2);
    const float4* mb4  = (const float4*)(mk + (size_t)b * IMG2);

    const int wid  = tid >> 6;            // 0..7 = row within tile
    const int lane = tid & 63;
    const int m16  = lane & 15;
    const int g    = lane >> 4;

    floatx4 D0 = {0.f, 0.f, 0.f, 0.f};
    floatx4 D1 = {0.f, 0.f, 0.f, 0.f};

    const uint4 onesbits = {0x3C003C00u, 0x3C003C00u, 0x3C003C00u, 0x3C003C00u};
    const uint4 zerobits = {0u, 0u, 0u, 0u};
    const half8 ones8 = __builtin_bit_cast(half8, onesbits);
    const half8 zero8 = __builtin_bit_cast(half8, zerobits);

    // edge slot: thread (i, t, kind) accumulates plane value at edge col
    float eacc = 0.f;
    int ei = 0, et = 0, ek = 0, ecolByte = 0;
    if (tid < 252) {
        ei = tid / 36; const int rem = tid % 36; et = rem % 12; ek = rem / 12;
        const int ec = (et < 6) ? et : (372 + et);
        ecolByte = 2 * ec;
    }

    // ---- 2-deep prefetch registers ----
    float4 qh[3], qm[3];
    float  ps0[3], ps1[3], pm0[3], pm1[3];

    auto qm_issue = [&](int t) {
        const int r0 = TROWS * t;
        #pragma unroll
        for (int k = 0; k < 3; ++k) {
            const int idx = tid + k * NTH;
            if (idx < NQM) {
                const int rw = idx / 96, c = idx % 96;
                int w = c0 + r0 + rw; if (w > 383) w = 383;   // clamp load only
                qh[k] = hb4[(size_t)w * IMG4 + c];
                qm[k] = mb4[(size_t)w * IMG4 + c];
            }
        }
    };
    auto qm_write = [&](int t) {
        #pragma unroll
        for (int k = 0; k < 3; ++k) {
            const int idx = tid + k * NTH;
            if (idx < NQM) {
                const int rw = idx / 96, c = idx % 96;
                const float4 hv = qh[k], mv = qm[k];
                const float qx = hv.x*mv.x, qy = hv.y*mv.y;
                const float qz = hv.z*mv.z, qw = hv.w*mv.w;
                *(uint2*)(qpl + rw*784 + c*8) = make_uint2(pkh(qx, qy), pkh(qz, qw));
                *(uint2*)(mpl + rw*784 + c*8) = make_uint2(pkh(mv.x, mv.y), pkh(mv.z, mv.w));
                atomicAdd(&rowQ2[t][rw], qx*qx + qy*qy + qz*qz + qw*qw);
            }
        }
    };
    auto p_issue = [&](int t) {
        const int r0 = TROWS * t;
        #pragma unroll
        for (int k = 0; k < 3; ++k) {
            const int idx = tid + k * NTH;
            if (idx < NP) {
                const int rw = idx / 189, d = 4 + idx % 189;  // x-dwords 4..192
                int rc = r0 + rw; if (c0 + rc > 377) rc = 377 - c0;
                const int v0 = 2*d - 8;
                const float* srow = sb   + (size_t)(c0 + rc + 3) * IMG + (v0 + 3);
                const float* mrow = mown + (size_t)(c0 + rc + 3) * IMG + (v0 + 3);
                ps0[k] = srow[0]; ps1[k] = srow[1];
                pm0[k] = mrow[0]; pm1[k] = mrow[1];
            }
        }
    };
    auto p_write = [&]() {
        #pragma unroll
        for (int k = 0; k < 3; ++k) {
            const int idx = tid + k * NTH;
            if (idx < NP) {
                const int rw = idx / 189, d = 4 + idx % 189;
                const float p0 = ps0[k] * pm0[k], p1 = ps1[k] * pm1[k];
                *(unsigned*)(ppl  + rw*800 + 4*d) = pkh(p0, p1);
                *(unsigned*)(p2pl + rw*800 + 4*d) = pkh(p0*p0, p1*p1);
            }
        }
    };

    // ---- prologue: zero rowQ2 + p-plane pads, issue tile 0 ----
    if (tid < TILES*16) ((float*)rowQ2)[tid] = 0.f;
    if (tid < 8*2*11) {                                   // p-plane pad dwords
        const int slot = tid / 22, rem = tid % 22;
        const int pl = rem / 11, kk = rem % 11;
        const int dd = (kk < 4) ? kk : (189 + kk);        // 0..3, 193..199
        *(unsigned*)((pl ? p2pl : ppl) + slot*800 + 4*dd) = 0u;
    }
    qm_issue(0);
    p_issue(0);
    __syncthreads();                                      // rowQ2/pads visible

    // ---- 3 tiles: write(t) -> barrier -> {issue(t+1) | compute(t)} -> barrier
    for (int t = 0; t < TILES; ++t) {
        qm_write(t);
        p_write();
        __syncthreads();

        if (t < TILES - 1) {          // issue next tile: overlaps MFMA below
            qm_issue(t + 1);
            p_issue(t + 1);
        }

        const int r0 = TROWS * t;
        if (r0 + wid < nvalid) {
            const int mm = (m16 < 7) ? m16 : (m16 - 7);
            const char* aB = ((m16 < 7) ? qpl : mpl) + (wid + mm)*784;
            const char* bB = ((m16 < 7) ? ppl : p2pl) + wid*800;
            const int Sb = 16 - 2*mm + g*16;
            #pragma unroll
            for (int sl = 0; sl < 12; ++sl) {
                half8 av, bv;
                if (m16 < 14) {
                    av = *(const half8*)(aB + sl*64 + g*16);
                    const int S  = Sb + sl*64;
                    const int S0 = S & ~3;
                    const unsigned sh = (unsigned)((S & 2) << 3);
                    const unsigned* bw = (const unsigned*)(bB + S0);
                    const unsigned d0 = bw[0], d1 = bw[1], d2 = bw[2], d3 = bw[3], d4 = bw[4];
                    uint4 bi;
                    bi.x = __builtin_amdgcn_alignbit(d1, d0, sh);
                    bi.y = __builtin_amdgcn_alignbit(d2, d1, sh);
                    bi.z = __builtin_amdgcn_alignbit(d3, d2, sh);
                    bi.w = __builtin_amdgcn_alignbit(d4, d3, sh);
                    bv = __builtin_bit_cast(half8, bi);
                } else if (m16 == 14) {
                    av = ones8; bv = ones8;
                } else {
                    av = zero8; bv = zero8;
                }
                if (sl & 1) D1 = __builtin_amdgcn_mfma_f32_16x16x32_f16(av, bv, D1, 0, 0, 0);
                else        D0 = __builtin_amdgcn_mfma_f32_16x16x32_f16(av, bv, D0, 0, 0, 0);
            }
        }

        // edges: window rows rel rr+ei (slot <= 13) for valid crop rows
        if (tid < 252) {
            #pragma unroll
            for (int rr = 0; rr < TROWS; ++rr) {
                if (r0 + rr < nvalid) {
                    const int slot = rr + ei;
                    const char* pl = (ek == 0) ? mpl : qpl;
                    const float v = (float)*(const __fp16*)(pl + slot*784 + ecolByte);
                    eacc += (ek == 2) ? v*v : v;
                }
            }
        }
        __syncthreads();      // protect planes from next tile's write
    }

    // ---- epilogue: reduce 8 waves' D (wred overlaid on dead p-planes) ----
    float* wred = (float*)ppool;              // 8*256 floats = 8 KB
    {
        const floatx4 D = D0 + D1;
        const int rb = (lane >> 4) * 4, col = lane & 15;
        #pragma unroll
        for (int k = 0; k < 4; ++k)
            wred[wid*256 + (rb + k)*16 + col] = D[k];
    }
    __syncthreads();
    float* po = part + (size_t)(b * NGRP + grp) * PSTR;
    if (tid < 256) {
        float v = 0.f;
        #pragma unroll
        for (int w = 0; w < 8; ++w) v += wred[w*256 + tid];
        po[tid] = v;
    }
    if (tid < 7) {
        float acc = 0.f;
        for (int t = 0; t < TILES; ++t) {
            int vt = nvalid - TROWS*t;
            vt = (vt < 0) ? 0 : (vt > TROWS ? TROWS : vt);
            for (int k = 0; k < vt; ++k) acc += rowQ2[t][tid + k];
        }
        po[256 + tid] = acc;
    }
    if (tid < 252)
        po[264 + ek*84 + ei*12 + et] = eacc;
}

__global__ __launch_bounds__(256)
void mse_kernel(const float* __restrict__ part, double* __restrict__ bmin)
{
    __shared__ double chunk[4][49][7];
    const int b   = blockIdx.x;
    const int tid = threadIdx.x;
    const int s   = tid & 63;            // shift 0..48 active
    const int cc  = tid >> 6;            // group chunk 0..3

    if (s < 49) {
        const int i = s / 7, j = s % 7;
        double A=0, Bc=0, Cc=0, Tm=0, Tq=0, Tq2=0, Sp=0;
        for (int gg = cc*4; gg < cc*4 + 4; ++gg) {
            const float* p = part + (size_t)(b * NGRP + gg) * PSTR;
            A   += p[i*16 + j];
            Cc  += p[(7+i)*16 + j];
            Bc  += p[(7+i)*16 + 7 + j];
            Tq  += p[i*16 + 14];
            Tm  += p[(7+i)*16 + 14];
            Sp  += p[14*16 + 0];
            Tq2 += p[256 + i];
            #pragma unroll
            for (int t = 0; t < 12; ++t) {
                if (t < j || t >= j + 6) {   // col outside x-window [j, j+377]
                    Tm  -= p[264 +      i*12 + t];
                    Tq  -= p[264 + 84 + i*12 + t];
                    Tq2 -= p[264 +168 + i*12 + t];
                }
            }
        }
        chunk[cc][s][0] = A;  chunk[cc][s][1] = Bc; chunk[cc][s][2] = Cc;
        chunk[cc][s][3] = Tm; chunk[cc][s][4] = Tq; chunk[cc][s][5] = Tq2;
        chunk[cc][s][6] = Sp;
    }
    __syncthreads();

    if (tid < 64) {
        double mse = 1e300;
        if (tid < 49) {
            double v[7];
            #pragma unroll
            for (int q = 0; q < 7; ++q)
                v[q] = chunk[0][tid][q] + chunk[1][tid][q] + chunk[2][tid][q] + chunk[3][tid][q];
            const double A = v[0], Bc = v[1], Cc = v[2], Tm = v[3];
            const double Tq = v[4], Tq2 = v[5], Sp = v[6];
            const double bb = (Tq - Sp) / Tm;
            mse = (Tq2 - 2.0*A - 2.0*bb*Tq + Bc + 2.0*bb*Cc + bb*bb*Tm) / Tm;
        }
        for (int off = 32; off; off >>= 1) {
            const double o = __shfl_down(mse, off);
            mse = fmin(mse, o);
        }
        if (tid == 0) bmin[b] = mse;
    }
}

__global__ __launch_bounds__(64)
void mean_kernel(const double* __restrict__ bmin, float* __restrict__ out)
{
    double v = bmin[threadIdx.x];
    for (int off = 32; off; off >>= 1) v += __shfl_down(v, off);
    if (threadIdx.x == 0) out[0] = (float)(v / 64.0);
}

extern "C" void kernel_launch(void* const* d_in, const int* in_sizes, int n_in,
                              void* d_out, int out_size, void* d_ws, size_t ws_size,
                              hipStream_t stream) {
    const float* sr = (const float*)d_in[0];
    const float* hr = (const float*)d_in[1];
    const float* mk = (const float*)d_in[2];

    float* part = (float*)d_ws;
    const size_t part_bytes = (size_t)NB * NGRP * PSTR * sizeof(float); // 2129920
    double* bmin = (double*)((char*)d_ws + part_bytes);

    corr_kernel<<<dim3(NB * NGRP), NTH, 0, stream>>>(sr, hr, mk, part);
    mse_kernel<<<dim3(NB), 256, 0, stream>>>(part, bmin);
    mean_kernel<<<dim3(1), 64, 0, stream>>>(bmin, (float*)d_out);
}

// Round 19
// 54.590 us; speedup vs baseline: 1.2883x; 1.2655x over previous
//
#include <hip/hip_runtime.h>

#define IMG   384
#define IMG4  96
#define IMG2  (IMG*IMG)
#define CROP  378
#define NB    64
#define NGRP  16
#define NROWS 24
#define NSTR  6           // stripes of 4 crop rows
#define NTH   256
#define PSTR  520         // 256 D + 8 Tq2 + 252 edges + pad

typedef __fp16 half8  __attribute__((ext_vector_type(8)));
typedef __fp16 f16x2  __attribute__((ext_vector_type(2)));
typedef float  floatx4 __attribute__((ext_vector_type(4)));

__device__ __forceinline__ unsigned pkh(float a, float b) {
    f16x2 h = __builtin_amdgcn_cvt_pkrtz(a, b);
    return __builtin_bit_cast(unsigned, h);
}

// R19 = R16 (verified best: corr 48us, total 58.6) + two surgical fixes:
//  (a) rowQ2 atomics split across 8 banks (was ~2880 same-address LDS
//      atomicAdds per block, serialized);
//  (b) edge gather on 84 threads reading q,m ONCE each (eM/eQ/eQ2 fused in
//      registers) instead of 252 threads reading each value 3x.
// MFMA formulation (verified R10+): one 16x16x32 f16 MFMA per
// (crop-row r, 32-wide u-slice):
//   A rows 0..6 = q[r+i][u], 7..13 = mask[r+i][u], 14 = ones, 15 = zero
//   B cols 0..6 = p[r][u-j], 7..13 = p^2[r][u-j], 14 = ones, 15 = zero
//   D[i][j]=A, D[7+i][j]=C, D[7+i][7+j]=B, D[i][14]=Tq(i), D[7+i][14]=Tm(i),
//   D[14][0]=Sp.  Tq2(i) from f32 per-row q^2 sums (rowQ2).
// Race safety per stripe s: compute+edge read q/m rels [4s..4s+9] (slots &15),
// p slots [4s..4s+3]&7; write q/m rels [4s+10..4s+13] (&15 disjoint), p rels
// [4s+4..4s+7] (&7 disjoint) -> single barrier per stripe.
__global__ __launch_bounds__(NTH)
void corr_kernel(const float* __restrict__ sr, const float* __restrict__ hr,
                 const float* __restrict__ mk, float* __restrict__ part)
{
    __shared__ __align__(16) char qpl [16*784];
    __shared__ __align__(16) char mpl [16*784];
    __shared__ __align__(16) char ppool[2*8*800 + 16];  // p2 staggered +16B
    __shared__ float rowQ2[32][8];                      // 8-bank split
    char* const ppl  = ppool;
    char* const p2pl = ppool + 8*800 + 16;

    const int tid = threadIdx.x;
    // XCD-clustered: all 16 blocks of a batch on one XCD class
    const int id  = blockIdx.x;
    const int c8  = id & 7;
    const int k0  = id >> 3;              // 0..127
    const int b   = c8 + 8 * (k0 >> 4);
    const int grp = k0 & 15;
    const int c0  = grp * NROWS;
    const int nvalid = (CROP - c0 < NROWS) ? (CROP - c0) : NROWS;

    const float*  sb   = sr + (size_t)b * IMG2;
    const float*  mown = mk + (size_t)b * IMG2;
    const float4* hb4  = (const float4*)(hr + (size_t)b * IMG2);
    const float4* mb4  = (const float4*)(mk + (size_t)b * IMG2);

    const int wid  = tid >> 6;            // 0..3 = row within stripe
    const int lane = tid & 63;
    const int m16  = lane & 15;
    const int g    = lane >> 4;
    const int bank = tid & 7;

    floatx4 D0 = {0.f, 0.f, 0.f, 0.f};
    floatx4 D1 = {0.f, 0.f, 0.f, 0.f};

    const uint4 onesbits = {0x3C003C00u, 0x3C003C00u, 0x3C003C00u, 0x3C003C00u};
    const uint4 zerobits = {0u, 0u, 0u, 0u};
    const half8 ones8 = __builtin_bit_cast(half8, onesbits);
    const half8 zero8 = __builtin_bit_cast(half8, zerobits);

    // edge slot (tid < 84): thread (i, t) reads q,m once, accumulates 3 kinds
    float eM = 0.f, eQ = 0.f, eQ2 = 0.f;
    int ei = 0, et = 0, ecolByte = 0;
    if (tid < 84) {
        ei = tid / 12; et = tid % 12;
        const int ec = (et < 6) ? et : (372 + et);
        ecolByte = 2 * ec;
    }

    // ---- T14 split staging: issue (global->reg) / write (reg->LDS) ----
    float4 hvr[2], mvr[2];
    auto qm_issue = [&](int relBase) {
        #pragma unroll
        for (int k = 0; k < 2; ++k) {
            const int idx = (tid + k * 256) % 384;     // dup items benign
            const int rw = idx / 96, c = idx % 96;
            int w = c0 + relBase + rw; if (w > 383) w = 383;
            hvr[k] = hb4[(size_t)w * IMG4 + c];
            mvr[k] = mb4[(size_t)w * IMG4 + c];
        }
    };
    auto qm_write = [&](int relBase) {
        #pragma unroll
        for (int k = 0; k < 2; ++k) {
            const int idx = (tid + k * 256) % 384;
            const int rw = idx / 96, c = idx % 96;
            const int rel = relBase + rw;
            const float4 hv = hvr[k], mv = mvr[k];
            const float qx = hv.x*mv.x, qy = hv.y*mv.y;
            const float qz = hv.z*mv.z, qw = hv.w*mv.w;
            const int slot = rel & 15;
            *(uint2*)(qpl + slot*784 + c*8) = make_uint2(pkh(qx, qy), pkh(qz, qw));
            *(uint2*)(mpl + slot*784 + c*8) = make_uint2(pkh(mv.x, mv.y), pkh(mv.z, mv.w));
            if (k == 0 || tid < 128)                    // unique writer only
                atomicAdd(&rowQ2[rel & 31][bank], qx*qx + qy*qy + qz*qz + qw*qw);
        }
    };
    float ps0[3], ps1[3], pm0[3], pm1[3];
    auto p_issue = [&](int relBase) {
        #pragma unroll
        for (int k = 0; k < 3; ++k) {
            const int idx = (tid + k * 256) % 756;     // dup items benign
            const int rw = idx / 189, d = 4 + idx % 189;
            int rc = relBase + rw; if (c0 + rc > 377) rc = 377 - c0;
            const int v0 = 2*d - 8;
            const float* srow = sb   + (size_t)(c0 + rc + 3) * IMG + (v0 + 3);
            const float* mrow = mown + (size_t)(c0 + rc + 3) * IMG + (v0 + 3);
            ps0[k] = srow[0]; ps1[k] = srow[1];
            pm0[k] = mrow[0]; pm1[k] = mrow[1];
        }
    };
    auto p_write = [&](int relBase) {
        #pragma unroll
        for (int k = 0; k < 3; ++k) {
            const int idx = (tid + k * 256) % 756;
            const int rw = idx / 189, d = 4 + idx % 189;
            const int rrel = relBase + rw;
            const float p0 = ps0[k] * pm0[k], p1 = ps1[k] * pm1[k];
            const int slot = rrel & 7;
            *(unsigned*)(ppl  + slot*800 + 4*d) = pkh(p0, p1);
            *(unsigned*)(p2pl + slot*800 + 4*d) = pkh(p0*p0, p1*p1);
        }
    };

    // ---- prologue: pads, qm rels 0..9, p rels 0..3 ----
    for (int idx = tid; idx < 8*2*11; idx += NTH) {       // p-plane pad dwords
        const int slot = idx / 22, rem = idx % 22;
        const int pl = rem / 11, kk = rem % 11;
        const int dd = (kk < 4) ? kk : (189 + kk);        // 0..3, 193..199
        *(unsigned*)((pl ? p2pl : ppl) + slot*800 + 4*dd) = 0u;
    }
    if (tid < 256) ((float*)rowQ2)[tid] = 0.f;
    __syncthreads();                                      // rowQ2 zero visible
    for (int idx = tid; idx < 10*96; idx += NTH) {        // qm rels 0..9
        const int rw = idx / 96, c = idx % 96;
        int w = c0 + rw; if (w > 383) w = 383;
        const float4 hv = hb4[(size_t)w * IMG4 + c];
        const float4 mv = mb4[(size_t)w * IMG4 + c];
        const float qx = hv.x*mv.x, qy = hv.y*mv.y;
        const float qz = hv.z*mv.z, qw = hv.w*mv.w;
        *(uint2*)(qpl + rw*784 + c*8) = make_uint2(pkh(qx, qy), pkh(qz, qw));
        *(uint2*)(mpl + rw*784 + c*8) = make_uint2(pkh(mv.x, mv.y), pkh(mv.z, mv.w));
        atomicAdd(&rowQ2[rw][bank], qx*qx + qy*qy + qz*qz + qw*qw);
    }
    p_issue(0);
    p_write(0);
    __syncthreads();

    // ---- main loop: single barrier per stripe ----
    for (int s = 0; s < NSTR; ++s) {
        const bool doStage = (s < NSTR - 1);
        if (doStage) {                       // issue-early
            qm_issue(4*s + 10);
            p_issue(4*s + 4);
        }
        __builtin_amdgcn_sched_barrier(0);

        const int lr = 4*s + wid;            // this wave's crop row
        if (lr < nvalid) {
            const int mm    = (m16 < 7) ? m16 : (m16 - 7);
            const int slotA = (lr + mm) & 15;
            const char* aB = ((m16 < 7) ? qpl : mpl) + slotA*784;
            const char* bB = ((m16 < 7) ? ppl : p2pl) + (lr & 7)*800;
            const int Sb = 16 - 2*mm + g*16;
            #pragma unroll
            for (int sl = 0; sl < 12; ++sl) {
                half8 av, bv;
                if (m16 < 14) {
                    av = *(const half8*)(aB + sl*64 + g*16);
                    const int S  = Sb + sl*64;
                    const int S0 = S & ~3;
                    const unsigned sh = (unsigned)((S & 2) << 3);
                    const unsigned* bw = (const unsigned*)(bB + S0);
                    const unsigned d0 = bw[0], d1 = bw[1], d2 = bw[2], d3 = bw[3], d4 = bw[4];
                    uint4 bi;
                    bi.x = __builtin_amdgcn_alignbit(d1, d0, sh);
                    bi.y = __builtin_amdgcn_alignbit(d2, d1, sh);
                    bi.z = __builtin_amdgcn_alignbit(d3, d2, sh);
                    bi.w = __builtin_amdgcn_alignbit(d4, d3, sh);
                    bv = __builtin_bit_cast(half8, bi);
                } else if (m16 == 14) {
                    av = ones8; bv = ones8;
                } else {
                    av = zero8; bv = zero8;
                }
                if (sl & 1) D1 = __builtin_amdgcn_mfma_f32_16x16x32_f16(av, bv, D1, 0, 0, 0);
                else        D0 = __builtin_amdgcn_mfma_f32_16x16x32_f16(av, bv, D0, 0, 0, 0);
            }
        }

        // edges: 84 threads, each reads q,m once per window row
        if (tid < 84) {
            #pragma unroll
            for (int rr = 0; rr < 4; ++rr) {
                if (4*s + rr < nvalid) {
                    const int slot = (4*s + rr + ei) & 15;
                    const float mv = (float)*(const __fp16*)(mpl + slot*784 + ecolByte);
                    const float qv = (float)*(const __fp16*)(qpl + slot*784 + ecolByte);
                    eM += mv;
                    eQ += qv;
                    eQ2 = fmaf(qv, qv, eQ2);
                }
            }
        }

        if (doStage) {                       // write-late
            qm_write(4*s + 10);
            p_write(4*s + 4);
        }
        __syncthreads();
    }

    // ---- reduce 4 waves' D (wred overlaid on dead p-planes), write record ----
    float* wred = (float*)ppool;             // 4*256 floats = 4 KB, p dead now
    {
        const floatx4 D = D0 + D1;
        const int rb = (lane >> 4) * 4, col = lane & 15;
        #pragma unroll
        for (int k = 0; k < 4; ++k)
            wred[wid*256 + (rb + k)*16 + col] = D[k];
    }
    __syncthreads();
    float* po = part + (size_t)(b * NGRP + grp) * PSTR;
    po[tid] = wred[tid] + wred[256 + tid] + wred[512 + tid] + wred[768 + tid];
    if (tid < 7) {
        float t = 0.f;
        for (int k = 0; k < nvalid; ++k) {
            const float* rq = rowQ2[tid + k];
            t += (rq[0] + rq[1]) + (rq[2] + rq[3]) + (rq[4] + rq[5]) + (rq[6] + rq[7]);
        }
        po[256 + tid] = t;
    }
    if (tid < 84) {
        po[264 +       ei*12 + et] = eM;
        po[264 +  84 + ei*12 + et] = eQ;
        po[264 + 168 + ei*12 + et] = eQ2;
    }
}

__global__ __launch_bounds__(256)
void mse_kernel(const float* __restrict__ part, double* __restrict__ bmin)
{
    __shared__ double chunk[4][49][7];
    const int b   = blockIdx.x;
    const int tid = threadIdx.x;
    const int s   = tid & 63;            // shift 0..48 active
    const int cc  = tid >> 6;            // group chunk 0..3

    if (s < 49) {
        const int i = s / 7, j = s % 7;
        double A=0, Bc=0, Cc=0, Tm=0, Tq=0, Tq2=0, Sp=0;
        for (int gg = cc*4; gg < cc*4 + 4; ++gg) {
            const float* p = part + (size_t)(b * NGRP + gg) * PSTR;
            A   += p[i*16 + j];
            Cc  += p[(7+i)*16 + j];
            Bc  += p[(7+i)*16 + 7 + j];
            Tq  += p[i*16 + 14];
            Tm  += p[(7+i)*16 + 14];
            Sp  += p[14*16 + 0];
            Tq2 += p[256 + i];
            #pragma unroll
            for (int t = 0; t < 12; ++t) {
                if (t < j || t >= j + 6) {   // col outside x-window [j, j+377]
                    Tm  -= p[264 +      i*12 + t];
                    Tq  -= p[264 + 84 + i*12 + t];
                    Tq2 -= p[264 +168 + i*12 + t];
                }
            }
        }
        chunk[cc][s][0] = A;  chunk[cc][s][1] = Bc; chunk[cc][s][2] = Cc;
        chunk[cc][s][3] = Tm; chunk[cc][s][4] = Tq; chunk[cc][s][5] = Tq2;
        chunk[cc][s][6] = Sp;
    }
    __syncthreads();

    if (tid < 64) {
        double mse = 1e300;
        if (tid < 49) {
            double v[7];
            #pragma unroll
            for (int q = 0; q < 7; ++q)
                v[q] = chunk[0][tid][q] + chunk[1][tid][q] + chunk[2][tid][q] + chunk[3][tid][q];
            const double A = v[0], Bc = v[1], Cc = v[2], Tm = v[3];
            const double Tq = v[4], Tq2 = v[5], Sp = v[6];
            const double bb = (Tq - Sp) / Tm;
            mse = (Tq2 - 2.0*A - 2.0*bb*Tq + Bc + 2.0*bb*Cc + bb*bb*Tm) / Tm;
        }
        for (int off = 32; off; off >>= 1) {
            const double o = __shfl_down(mse, off);
            mse = fmin(mse, o);
        }
        if (tid == 0) bmin[b] = mse;
    }
}

__global__ __launch_bounds__(64)
void mean_kernel(const double* __restrict__ bmin, float* __restrict__ out)
{
    double v = bmin[threadIdx.x];
    for (int off = 32; off; off >>= 1) v += __shfl_down(v, off);
    if (threadIdx.x == 0) out[0] = (float)(v / 64.0);
}

extern "C" void kernel_launch(void* const* d_in, const int* in_sizes, int n_in,
                              void* d_out, int out_size, void* d_ws, size_t ws_size,
                              hipStream_t stream) {
    const float* sr = (const float*)d_in[0];
    const float* hr = (const float*)d_in[1];
    const float* mk = (const float*)d_in[2];

    float* part = (float*)d_ws;
    const size_t part_bytes = (size_t)NB * NGRP * PSTR * sizeof(float); // 2129920
    double* bmin = (double*)((char*)d_ws + part_bytes);

    corr_kernel<<<dim3(NB * NGRP), NTH, 0, stream>>>(sr, hr, mk, part);
    mse_kernel<<<dim3(NB), 256, 0, stream>>>(part, bmin);
    mean_kernel<<<dim3(1), 64, 0, stream>>>(bmin, (float*)d_out);
}

// Round 20
// 49.711 us; speedup vs baseline: 1.4148x; 1.0981x over previous
//
#include <hip/hip_runtime.h>

#define IMG   384
#define IMG4  96
#define IMG2  (IMG*IMG)
#define CROP  378
#define NB    64
#define NGRP  16
#define NROWS 24
#define NSTR  6           // stripes of 4 crop rows
#define NTH   256
#define PSTR  520         // 256 D + 8 Tq2 + 252 edges + pad

typedef __fp16 half8  __attribute__((ext_vector_type(8)));
typedef __fp16 f16x2  __attribute__((ext_vector_type(2)));
typedef float  floatx4 __attribute__((ext_vector_type(4)));

__device__ __forceinline__ unsigned pkh(float a, float b) {
    f16x2 h = __builtin_amdgcn_cvt_pkrtz(a, b);
    return __builtin_bit_cast(unsigned, h);
}

// R20 = R19 minus the p2 LDS plane:
//  p^2-fragment is computed IN REGISTERS as (p-fragment)^2 after alignbit
//  (4 v_pk_mul_f16) — mask-lanes read the SAME ppl dwords as their paired
//  p-lanes (LDS broadcast, free). Removes 6.4 KB LDS + half the p staging
//  writes + the ppl/p2pl cross-plane bank aliasing.
//  LDS 39424 -> ~32256 => 5 blocks/CU => all 1024 blocks co-resident.
// MFMA formulation (verified R10+): one 16x16x32 f16 MFMA per
// (crop-row r, 32-wide u-slice):
//   A rows 0..6 = q[r+i][u], 7..13 = mask[r+i][u], 14 = ones, 15 = zero
//   B cols 0..6 = p[r][u-j], 7..13 = p^2[r][u-j], 14 = ones, 15 = zero
//   D[i][j]=A, D[7+i][j]=C, D[7+i][7+j]=B, D[i][14]=Tq(i), D[7+i][14]=Tm(i),
//   D[14][0]=Sp.  Tq2(i) from f32 per-row q^2 sums (rowQ2).
// Race safety per stripe s: compute+edge read q/m rels [4s..4s+9] (slots &15),
// p slots [4s..4s+3]&7; write q/m rels [4s+10..4s+13] (&15 disjoint), p rels
// [4s+4..4s+7] (&7 disjoint) -> single barrier per stripe.
__global__ __launch_bounds__(NTH)
void corr_kernel(const float* __restrict__ sr, const float* __restrict__ hr,
                 const float* __restrict__ mk, float* __restrict__ part)
{
    __shared__ __align__(16) char qpl [16*784];
    __shared__ __align__(16) char mpl [16*784];
    __shared__ __align__(16) char ppl [8*800];
    __shared__ float rowQ2[32][4];                      // 4-bank split
    // epilogue wred (4 KB) overlays dead ppl (6.4 KB)

    const int tid = threadIdx.x;
    // XCD-clustered: all 16 blocks of a batch on one XCD class
    const int id  = blockIdx.x;
    const int c8  = id & 7;
    const int k0  = id >> 3;              // 0..127
    const int b   = c8 + 8 * (k0 >> 4);
    const int grp = k0 & 15;
    const int c0  = grp * NROWS;
    const int nvalid = (CROP - c0 < NROWS) ? (CROP - c0) : NROWS;

    const float*  sb   = sr + (size_t)b * IMG2;
    const float*  mown = mk + (size_t)b * IMG2;
    const float4* hb4  = (const float4*)(hr + (size_t)b * IMG2);
    const float4* mb4  = (const float4*)(mk + (size_t)b * IMG2);

    const int wid  = tid >> 6;            // 0..3 = row within stripe
    const int lane = tid & 63;
    const int m16  = lane & 15;
    const int g    = lane >> 4;
    const int bank = tid & 3;

    floatx4 D0 = {0.f, 0.f, 0.f, 0.f};
    floatx4 D1 = {0.f, 0.f, 0.f, 0.f};

    const uint4 onesbits = {0x3C003C00u, 0x3C003C00u, 0x3C003C00u, 0x3C003C00u};
    const uint4 zerobits = {0u, 0u, 0u, 0u};
    const half8 ones8 = __builtin_bit_cast(half8, onesbits);
    const half8 zero8 = __builtin_bit_cast(half8, zerobits);

    // edge slot (tid < 84): thread (i, t) reads q,m once, accumulates 3 kinds
    float eM = 0.f, eQ = 0.f, eQ2 = 0.f;
    int ei = 0, et = 0, ecolByte = 0;
    if (tid < 84) {
        ei = tid / 12; et = tid % 12;
        const int ec = (et < 6) ? et : (372 + et);
        ecolByte = 2 * ec;
    }

    // ---- T14 split staging: issue (global->reg) / write (reg->LDS) ----
    float4 hvr[2], mvr[2];
    auto qm_issue = [&](int relBase) {
        #pragma unroll
        for (int k = 0; k < 2; ++k) {
            const int idx = (tid + k * 256) % 384;     // dup items benign
            const int rw = idx / 96, c = idx % 96;
            int w = c0 + relBase + rw; if (w > 383) w = 383;
            hvr[k] = hb4[(size_t)w * IMG4 + c];
            mvr[k] = mb4[(size_t)w * IMG4 + c];
        }
    };
    auto qm_write = [&](int relBase) {
        #pragma unroll
        for (int k = 0; k < 2; ++k) {
            const int idx = (tid + k * 256) % 384;
            const int rw = idx / 96, c = idx % 96;
            const int rel = relBase + rw;
            const float4 hv = hvr[k], mv = mvr[k];
            const float qx = hv.x*mv.x, qy = hv.y*mv.y;
            const float qz = hv.z*mv.z, qw = hv.w*mv.w;
            const int slot = rel & 15;
            *(uint2*)(qpl + slot*784 + c*8) = make_uint2(pkh(qx, qy), pkh(qz, qw));
            *(uint2*)(mpl + slot*784 + c*8) = make_uint2(pkh(mv.x, mv.y), pkh(mv.z, mv.w));
            if (k == 0 || tid < 128)                    // unique writer only
                atomicAdd(&rowQ2[rel & 31][bank], qx*qx + qy*qy + qz*qz + qw*qw);
        }
    };
    float ps0[3], ps1[3], pm0[3], pm1[3];
    auto p_issue = [&](int relBase) {
        #pragma unroll
        for (int k = 0; k < 3; ++k) {
            const int idx = (tid + k * 256) % 756;     // dup items benign
            const int rw = idx / 189, d = 4 + idx % 189;
            int rc = relBase + rw; if (c0 + rc > 377) rc = 377 - c0;
            const int v0 = 2*d - 8;
            const float* srow = sb   + (size_t)(c0 + rc + 3) * IMG + (v0 + 3);
            const float* mrow = mown + (size_t)(c0 + rc + 3) * IMG + (v0 + 3);
            ps0[k] = srow[0]; ps1[k] = srow[1];
            pm0[k] = mrow[0]; pm1[k] = mrow[1];
        }
    };
    auto p_write = [&](int relBase) {
        #pragma unroll
        for (int k = 0; k < 3; ++k) {
            const int idx = (tid + k * 256) % 756;
            const int rw = idx / 189, d = 4 + idx % 189;
            const int rrel = relBase + rw;
            const float p0 = ps0[k] * pm0[k], p1 = ps1[k] * pm1[k];
            *(unsigned*)(ppl + (rrel & 7)*800 + 4*d) = pkh(p0, p1);
        }
    };

    // ---- prologue: pads, qm rels 0..9, p rels 0..3 ----
    if (tid < 8*11) {                                     // p-plane pad dwords
        const int slot = tid / 11, kk = tid % 11;
        const int dd = (kk < 4) ? kk : (189 + kk);        // 0..3, 193..199
        *(unsigned*)(ppl + slot*800 + 4*dd) = 0u;
    }
    if (tid < 128) ((float*)rowQ2)[tid] = 0.f;
    __syncthreads();                                      // rowQ2 zero visible
    for (int idx = tid; idx < 10*96; idx += NTH) {        // qm rels 0..9
        const int rw = idx / 96, c = idx % 96;
        int w = c0 + rw; if (w > 383) w = 383;
        const float4 hv = hb4[(size_t)w * IMG4 + c];
        const float4 mv = mb4[(size_t)w * IMG4 + c];
        const float qx = hv.x*mv.x, qy = hv.y*mv.y;
        const float qz = hv.z*mv.z, qw = hv.w*mv.w;
        *(uint2*)(qpl + rw*784 + c*8) = make_uint2(pkh(qx, qy), pkh(qz, qw));
        *(uint2*)(mpl + rw*784 + c*8) = make_uint2(pkh(mv.x, mv.y), pkh(mv.z, mv.w));
        atomicAdd(&rowQ2[rw][bank], qx*qx + qy*qy + qz*qz + qw*qw);
    }
    p_issue(0);
    p_write(0);
    __syncthreads();

    // ---- main loop: single barrier per stripe ----
    for (int s = 0; s < NSTR; ++s) {
        const bool doStage = (s < NSTR - 1);
        if (doStage) {                       // issue-early
            qm_issue(4*s + 10);
            p_issue(4*s + 4);
        }
        __builtin_amdgcn_sched_barrier(0);

        const int lr = 4*s + wid;            // this wave's crop row
        if (lr < nvalid) {
            const int mm    = (m16 < 7) ? m16 : (m16 - 7);
            const int slotA = (lr + mm) & 15;
            const char* aB = ((m16 < 7) ? qpl : mpl) + slotA*784;
            const char* bB = ppl + (lr & 7)*800;
            const int Sb = 16 - 2*mm + g*16;
            #pragma unroll
            for (int sl = 0; sl < 12; ++sl) {
                half8 av, bv;
                if (m16 < 14) {
                    av = *(const half8*)(aB + sl*64 + g*16);
                    const int S  = Sb + sl*64;
                    const int S0 = S & ~3;
                    const unsigned sh = (unsigned)((S & 2) << 3);
                    const unsigned* bw = (const unsigned*)(bB + S0);
                    const unsigned d0 = bw[0], d1 = bw[1], d2 = bw[2], d3 = bw[3], d4 = bw[4];
                    uint4 bi;
                    bi.x = __builtin_amdgcn_alignbit(d1, d0, sh);
                    bi.y = __builtin_amdgcn_alignbit(d2, d1, sh);
                    bi.z = __builtin_amdgcn_alignbit(d3, d2, sh);
                    bi.w = __builtin_amdgcn_alignbit(d4, d3, sh);
                    bv = __builtin_bit_cast(half8, bi);
                    if (m16 >= 7) bv = bv * bv;          // p^2 in registers
                } else if (m16 == 14) {
                    av = ones8; bv = ones8;
                } else {
                    av = zero8; bv = zero8;
                }
                if (sl & 1) D1 = __builtin_amdgcn_mfma_f32_16x16x32_f16(av, bv, D1, 0, 0, 0);
                else        D0 = __builtin_amdgcn_mfma_f32_16x16x32_f16(av, bv, D0, 0, 0, 0);
            }
        }

        // edges: 84 threads, each reads q,m once per window row
        if (tid < 84) {
            #pragma unroll
            for (int rr = 0; rr < 4; ++rr) {
                if (4*s + rr < nvalid) {
                    const int slot = (4*s + rr + ei) & 15;
                    const float mv = (float)*(const __fp16*)(mpl + slot*784 + ecolByte);
                    const float qv = (float)*(const __fp16*)(qpl + slot*784 + ecolByte);
                    eM += mv;
                    eQ += qv;
                    eQ2 = fmaf(qv, qv, eQ2);
                }
            }
        }

        if (doStage) {                       // write-late
            qm_write(4*s + 10);
            p_write(4*s + 4);
        }
        __syncthreads();
    }

    // ---- reduce 4 waves' D (wred overlaid on dead ppl), write record ----
    float* wred = (float*)ppl;               // 4*256 floats = 4 KB <= 6.4 KB
    {
        const floatx4 D = D0 + D1;
        const int rb = (lane >> 4) * 4, col = lane & 15;
        #pragma unroll
        for (int k = 0; k < 4; ++k)
            wred[wid*256 + (rb + k)*16 + col] = D[k];
    }
    __syncthreads();
    float* po = part + (size_t)(b * NGRP + grp) * PSTR;
    po[tid] = wred[tid] + wred[256 + tid] + wred[512 + tid] + wred[768 + tid];
    if (tid < 7) {
        float t = 0.f;
        for (int k = 0; k < nvalid; ++k) {
            const float* rq = rowQ2[tid + k];
            t += (rq[0] + rq[1]) + (rq[2] + rq[3]);
        }
        po[256 + tid] = t;
    }
    if (tid < 84) {
        po[264 +       ei*12 + et] = eM;
        po[264 +  84 + ei*12 + et] = eQ;
        po[264 + 168 + ei*12 + et] = eQ2;
    }
}

__global__ __launch_bounds__(256)
void mse_kernel(const float* __restrict__ part, double* __restrict__ bmin)
{
    __shared__ double chunk[4][49][7];
    const int b   = blockIdx.x;
    const int tid = threadIdx.x;
    const int s   = tid & 63;            // shift 0..48 active
    const int cc  = tid >> 6;            // group chunk 0..3

    if (s < 49) {
        const int i = s / 7, j = s % 7;
        double A=0, Bc=0, Cc=0, Tm=0, Tq=0, Tq2=0, Sp=0;
        for (int gg = cc*4; gg < cc*4 + 4; ++gg) {
            const float* p = part + (size_t)(b * NGRP + gg) * PSTR;
            A   += p[i*16 + j];
            Cc  += p[(7+i)*16 + j];
            Bc  += p[(7+i)*16 + 7 + j];
            Tq  += p[i*16 + 14];
            Tm  += p[(7+i)*16 + 14];
            Sp  += p[14*16 + 0];
            Tq2 += p[256 + i];
            #pragma unroll
            for (int t = 0; t < 12; ++t) {
                if (t < j || t >= j + 6) {   // col outside x-window [j, j+377]
                    Tm  -= p[264 +      i*12 + t];
                    Tq  -= p[264 + 84 + i*12 + t];
                    Tq2 -= p[264 +168 + i*12 + t];
                }
            }
        }
        chunk[cc][s][0] = A;  chunk[cc][s][1] = Bc; chunk[cc][s][2] = Cc;
        chunk[cc][s][3] = Tm; chunk[cc][s][4] = Tq; chunk[cc][s][5] = Tq2;
        chunk[cc][s][6] = Sp;
    }
    __syncthreads();

    if (tid < 64) {
        double mse = 1e300;
        if (tid < 49) {
            double v[7];
            #pragma unroll
            for (int q = 0; q < 7; ++q)
                v[q] = chunk[0][tid][q] + chunk[1][tid][q] + chunk[2][tid][q] + chunk[3][tid][q];
            const double A = v[0], Bc = v[1], Cc = v[2], Tm = v[3];
            const double Tq = v[4], Tq2 = v[5], Sp = v[6];
            const double bb = (Tq - Sp) / Tm;
            mse = (Tq2 - 2.0*A - 2.0*bb*Tq + Bc + 2.0*bb*Cc + bb*bb*Tm) / Tm;
        }
        for (int off = 32; off; off >>= 1) {
            const double o = __shfl_down(mse, off);
            mse = fmin(mse, o);
        }
        if (tid == 0) bmin[b] = mse;
    }
}

__global__ __launch_bounds__(64)
void mean_kernel(const double* __restrict__ bmin, float* __restrict__ out)
{
    double v = bmin[threadIdx.x];
    for (int off = 32; off; off >>= 1) v += __shfl_down(v, off);
    if (threadIdx.x == 0) out[0] = (float)(v / 64.0);
}

extern "C" void kernel_launch(void* const* d_in, const int* in_sizes, int n_in,
                              void* d_out, int out_size, void* d_ws, size_t ws_size,
                              hipStream_t stream) {
    const float* sr = (const float*)d_in[0];
    const float* hr = (const float*)d_in[1];
    const float* mk = (const float*)d_in[2];

    float* part = (float*)d_ws;
    const size_t part_bytes = (size_t)NB * NGRP * PSTR * sizeof(float); // 2129920
    double* bmin = (double*)((char*)d_ws + part_bytes);

    corr_kernel<<<dim3(NB * NGRP), NTH, 0, stream>>>(sr, hr, mk, part);
    mse_kernel<<<dim3(NB), 256, 0, stream>>>(part, bmin);
    mean_kernel<<<dim3(1), 64, 0, stream>>>(bmin, (float*)d_out);
}